// Round 7
// baseline (157.625 us; speedup 1.0000x reference)
//
#include <hip/hip_runtime.h>

#define NNODES 4096
#define DIM 512
#define QKVD 1536
#define MAXE 96  // bucket capacity per dst row (Poisson(32): P(deg>96) ~ 1e-18)

typedef __bf16 bf16_t;
typedef bf16_t bf16x8 __attribute__((ext_vector_type(8)));
typedef bf16_t bf16x2 __attribute__((ext_vector_type(2)));
typedef float f32x4 __attribute__((ext_vector_type(4)));
typedef unsigned int uint;

// ---------------- fused casts f32 -> bf16 (+ deg zero) ----------------
__global__ __launch_bounds__(256) void cast_all_k(const float* __restrict__ x,
                                                  const float* __restrict__ wqkv,
                                                  const float* __restrict__ wo,
                                                  const float* __restrict__ w1,
                                                  bf16_t* __restrict__ xb,
                                                  bf16_t* __restrict__ wqkvb,
                                                  bf16_t* __restrict__ wob,
                                                  bf16_t* __restrict__ w1b,
                                                  uint* __restrict__ deg) {
  int i = blockIdx.x * 256 + threadIdx.x;
  if (blockIdx.x < 16) deg[i] = 0u;  // 16*256 = 4096 rows
  const float* src;
  bf16_t* dst;
  int off;
  if (i < 524288) { src = x; dst = xb; off = i; }
  else if (i < 720896) { src = wqkv; dst = wqkvb; off = i - 524288; }
  else if (i < 786432) { src = wo; dst = wob; off = i - 720896; }
  else { src = w1; dst = w1b; off = i - 786432; }
  float4 v = ((const float4*)src)[off];
  dst[4 * off + 0] = (bf16_t)v.x;
  dst[4 * off + 1] = (bf16_t)v.y;
  dst[4 * off + 2] = (bf16_t)v.z;
  dst[4 * off + 3] = (bf16_t)v.w;
}

// ---------------- bucket CSR fill ----------------
__global__ __launch_bounds__(256) void fill_bucket_k(const int* __restrict__ ei,
                                                     uint* __restrict__ deg,
                                                     int* __restrict__ colv,
                                                     uint* __restrict__ eidv, int E) {
  int e = blockIdx.x * 256 + threadIdx.x;
  if (e < E) {
    int src = ei[e] & (NNODES - 1);
    int dst = ei[E + e] & (NNODES - 1);
    uint pos = atomicAdd(&deg[dst], 1u);
    if (pos < MAXE) {
      colv[dst * MAXE + pos] = src;
      eidv[dst * MAXE + pos] = (uint)e + 1u;  // 0 reserved for diagonal self-entry
    }
  }
}

// ---------------- bf16 MFMA GEMM: C = A @ B^T + bias, tile 128x64 ----------------
// MODE 0: f32 row-major out. MODE 1: bf16 row-major out.
// MODE 2 (QKV): bf16 split layout: Q[m][0..512) | Kh[h][m][64] | Vh[h][m][64]
template <int MODE>
__global__ __launch_bounds__(256) void gemm_bt(const bf16_t* __restrict__ A,
                                               const bf16_t* __restrict__ B,
                                               const float* __restrict__ bias,
                                               void* __restrict__ Cout,
                                               int M, int Nt, int K) {
  __shared__ bf16_t As[128][40];
  __shared__ bf16_t Bs[64][40];
  const int t = threadIdx.x;
  const int lane = t & 63, w = t >> 6;
  const int wr = (w >> 1) * 64, wc = (w & 1) * 32;
  const int m0 = blockIdx.y * 128, n0 = blockIdx.x * 64;
  f32x4 acc[4][2] = {};
  const int r_ld = t >> 2;
  const int c_ld = (t & 3) * 8;

  for (int k0 = 0; k0 < K; k0 += 32) {
    *(int4*)&As[r_ld][c_ld] = *(const int4*)(A + (long)(m0 + r_ld) * K + k0 + c_ld);
    *(int4*)&As[r_ld + 64][c_ld] = *(const int4*)(A + (long)(m0 + r_ld + 64) * K + k0 + c_ld);
    *(int4*)&Bs[r_ld][c_ld] = *(const int4*)(B + (long)(n0 + r_ld) * K + k0 + c_ld);
    __syncthreads();
    bf16x8 af[4], bfr[2];
    const int kg = (lane >> 4) * 8;
#pragma unroll
    for (int i = 0; i < 4; ++i)
      af[i] = *(const bf16x8*)&As[wr + i * 16 + (lane & 15)][kg];
#pragma unroll
    for (int j = 0; j < 2; ++j)
      bfr[j] = *(const bf16x8*)&Bs[wc + j * 16 + (lane & 15)][kg];
#pragma unroll
    for (int i = 0; i < 4; ++i)
#pragma unroll
      for (int j = 0; j < 2; ++j)
        acc[i][j] = __builtin_amdgcn_mfma_f32_16x16x32_bf16(af[i], bfr[j], acc[i][j], 0, 0, 0);
    __syncthreads();
  }

  const int cr = (lane >> 4) * 4;
  const int cc = lane & 15;
#pragma unroll
  for (int i = 0; i < 4; ++i) {
#pragma unroll
    for (int j = 0; j < 2; ++j) {
      int n = n0 + wc + j * 16 + cc;
      float bv = bias[n];
#pragma unroll
      for (int r = 0; r < 4; ++r) {
        int m = m0 + wr + i * 16 + cr + r;
        float vv = acc[i][j][r] + bv;
        if (MODE == 0) {
          ((float*)Cout)[(long)m * Nt + n] = vv;
        } else if (MODE == 1) {
          ((bf16_t*)Cout)[(long)m * Nt + n] = (bf16_t)vv;
        } else {
          bf16_t* C = (bf16_t*)Cout;
          if (n < 512) {
            C[(long)m * 512 + n] = (bf16_t)vv;  // Q row-major
          } else {
            int reg = (n >= 1024);               // 0=K, 1=V
            int h = (n - 512 - reg * 512) >> 6;  // head
            int d = n & 63;                      // dim within head
            C[2097152 + (long)reg * 2097152 + h * 262144 + (long)m * 64 + d] = (bf16_t)vv;
          }
        }
      }
    }
  }
}

// ---------------- head-group sparse attention: scores + softmax + PV ----------------
// grid (NNODES, 4 head-groups); block 256 thr = 4 waves; each block handles 2 heads
// K/V head-sliced: per-hg working set 2MB -> fits per-XCD L2
__global__ __launch_bounds__(256) void attn_hg_k(const bf16_t* __restrict__ qb,
                                                 const bf16_t* __restrict__ kh,
                                                 const bf16_t* __restrict__ vh,
                                                 const float* __restrict__ ew,
                                                 const uint* __restrict__ deg,
                                                 const int* __restrict__ colv,
                                                 const uint* __restrict__ eidv,
                                                 bf16_t* __restrict__ outb) {
  __shared__ float scs[2][MAXE + 1];
  __shared__ int srcs[MAXE + 1];
  __shared__ uint eids[MAXE + 1];
  __shared__ int vld[MAXE + 1];
  __shared__ float invs_s[2];
  __shared__ float vacc[4][128];

  const int i = blockIdx.x;
  const int hg = blockIdx.y;
  const int t = threadIdx.x;
  const int lane = t & 63, w = t >> 6;
  const int hl = lane >> 5;        // head within group: 0/1
  const int dl = (lane & 31) * 2;  // dim pair within head

  uint dg = deg[i];
  int L = (dg < (uint)MAXE) ? (int)dg : MAXE;
  int n = L + 1;

  if (t < L) {
    srcs[t] = colv[i * MAXE + t];
    eids[t] = eidv[i * MAXE + t];
  }
  if (t == L) { srcs[L] = i; eids[L] = 0u; }
  __syncthreads();

  // deterministic dedupe (last edge-id wins per src), branchless
  if (t < n) {
    int sj = srcs[t];
    uint my = eids[t];
    int ok = 1;
    for (int j = 0; j < n; ++j)
      ok &= !((srcs[j] == sj) & (eids[j] > my));
    vld[t] = ok;
  }
  __syncthreads();

  const int h = hg * 2 + hl;                   // global head
  const long hb = (long)h * (NNODES * 64);     // head slice base
  float q0, q1;
  {
    bf16x2 qv = *(const bf16x2*)(qb + (long)i * 512 + h * 64 + dl);
    q0 = (float)qv[0];
    q1 = (float)qv[1];
  }

  // scores: wave w -> entries w, w+4, ... ; 4 clamped loads per batch (256B/entry)
  for (int e = w; e < n; e += 16) {
    int ec[4], val[4];
#pragma unroll
    for (int u = 0; u < 4; ++u) {
      int ee = e + u * 4;
      val[u] = ee < n;
      ec[u] = val[u] ? ee : e;
    }
    bf16x2 kr[4];
#pragma unroll
    for (int u = 0; u < 4; ++u)
      kr[u] = *(const bf16x2*)(kh + hb + (long)srcs[ec[u]] * 64 + dl);
    float d[4];
#pragma unroll
    for (int u = 0; u < 4; ++u) d[u] = q0 * (float)kr[u][0] + q1 * (float)kr[u][1];
#pragma unroll
    for (int o = 1; o < 32; o <<= 1) {
#pragma unroll
      for (int u = 0; u < 4; ++u) d[u] += __shfl_xor(d[u], o);
    }
    if ((lane & 31) == 0) {
#pragma unroll
      for (int u = 0; u < 4; ++u) {
        if (val[u]) {
          uint id = eids[ec[u]];
          float b = (id == 0u) ? 0.f : ew[id - 1u];
          scs[hl][ec[u]] = vld[ec[u]] ? (d[u] * 0.125f + b) : -1e30f;
        }
      }
    }
  }
  __syncthreads();

  // softmax: wave 0 -> head 0, wave 1 -> head 1
  if (w < 2) {
    float m = -1e30f;
    for (int e = lane; e < n; e += 64) m = fmaxf(m, scs[w][e]);
#pragma unroll
    for (int o = 32; o > 0; o >>= 1) m = fmaxf(m, __shfl_xor(m, o));
    float ps = 0.f;
    for (int e = lane; e < n; e += 64) {
      float ev = __expf(scs[w][e] - m);
      scs[w][e] = ev;  // invalid entries become exactly 0
      ps += ev;
    }
#pragma unroll
    for (int o = 32; o > 0; o >>= 1) ps += __shfl_xor(ps, o);
    if (lane == 0) invs_s[w] = 1.f / ps;
  }
  __syncthreads();

  // PV: wave w -> entries w, w+4, ...; lane covers (head hl, dims dl..dl+1)
  float a0 = 0.f, a1 = 0.f;
  for (int e = w; e < n; e += 16) {
    int ec[4];
    float p[4];
#pragma unroll
    for (int u = 0; u < 4; ++u) {
      int ee = e + u * 4;
      int vu = ee < n;
      ec[u] = vu ? ee : e;
      p[u] = vu ? scs[hl][ec[u]] : 0.f;
    }
    bf16x2 vr[4];
#pragma unroll
    for (int u = 0; u < 4; ++u)
      vr[u] = *(const bf16x2*)(vh + hb + (long)srcs[ec[u]] * 64 + dl);
#pragma unroll
    for (int u = 0; u < 4; ++u) {
      a0 += p[u] * (float)vr[u][0];
      a1 += p[u] * (float)vr[u][1];
    }
  }
  vacc[w][hl * 64 + dl] = a0;
  vacc[w][hl * 64 + dl + 1] = a1;
  __syncthreads();

  // final reduce over 4 wave-partials: thread t<64 -> dims 2t, 2t+1 of the 128-dim slice
  if (t < 64) {
    int d0 = 2 * t;
    float inv = invs_s[d0 >> 6];
    float s0 = vacc[0][d0] + vacc[1][d0] + vacc[2][d0] + vacc[3][d0];
    float s1 = vacc[0][d0 + 1] + vacc[1][d0 + 1] + vacc[2][d0 + 1] + vacc[3][d0 + 1];
    bf16x2 o2;
    o2[0] = (bf16_t)(s0 * inv);
    o2[1] = (bf16_t)(s1 * inv);
    *(bf16x2*)(outb + (long)i * 512 + hg * 128 + d0) = o2;
  }
}

// ---------------- LayerNorm(a+b) ----------------
__global__ __launch_bounds__(64) void ln_k(const float* __restrict__ a,
                                           const float* __restrict__ b,
                                           const float* __restrict__ g,
                                           const float* __restrict__ beta,
                                           float* __restrict__ of,
                                           bf16_t* __restrict__ ob) {
  const int row = blockIdx.x;
  const int l = threadIdx.x;
  const float* pa = a + (long)row * DIM;
  const float* pb = b + (long)row * DIM;
  float v[8];
  float s = 0.f;
#pragma unroll
  for (int j = 0; j < 8; ++j) {
    int d = l + j * 64;
    v[j] = pa[d] + pb[d];
    s += v[j];
  }
#pragma unroll
  for (int o = 32; o > 0; o >>= 1) s += __shfl_xor(s, o);
  float mu = s * (1.f / 512.f);
  float q = 0.f;
#pragma unroll
  for (int j = 0; j < 8; ++j) {
    float dd = v[j] - mu;
    q += dd * dd;
  }
#pragma unroll
  for (int o = 32; o > 0; o >>= 1) q += __shfl_xor(q, o);
  float inv = rsqrtf(q * (1.f / 512.f) + 1e-5f);
#pragma unroll
  for (int j = 0; j < 8; ++j) {
    int d = l + j * 64;
    float y = (v[j] - mu) * inv * g[d] + beta[d];
    of[(long)row * DIM + d] = y;
    if (ob) ob[(long)row * DIM + d] = (bf16_t)y;
  }
}

// ---------------- launch ----------------
extern "C" void kernel_launch(void* const* d_in, const int* in_sizes, int n_in,
                              void* d_out, int out_size, void* d_ws, size_t ws_size,
                              hipStream_t stream) {
  const float* x = (const float*)d_in[0];
  const int* ei = (const int*)d_in[1];
  const float* ew = (const float*)d_in[2];
  const float* Wqkv = (const float*)d_in[3];
  const float* bqkv = (const float*)d_in[4];
  const float* Wo = (const float*)d_in[5];
  const float* bo = (const float*)d_in[6];
  const float* W1 = (const float*)d_in[7];
  const float* b1 = (const float*)d_in[8];
  const float* g1 = (const float*)d_in[9];
  const float* be1 = (const float*)d_in[10];
  const float* g2 = (const float*)d_in[11];
  const float* be2 = (const float*)d_in[12];
  float* out = (float*)d_out;
  const int E = in_sizes[1] / 2;

  char* ws = (char*)d_ws;
  bf16_t* qsplit = (bf16_t*)(ws + 0);         // 12,582,912 B: Q 4MB | Kh 4MB | Vh 4MB
  bf16_t* qb = qsplit;
  bf16_t* khp = qsplit + 2097152;
  bf16_t* vhp = qsplit + 4194304;
  bf16_t* xb = (bf16_t*)(ws + 12582912);      // 4,194,304
  bf16_t* Wqkvb = (bf16_t*)(ws + 16777216);   // 1,572,864
  bf16_t* Wob = (bf16_t*)(ws + 18350080);     // 524,288
  bf16_t* W1b = (bf16_t*)(ws + 18874368);     // 524,288
  bf16_t* outb = (bf16_t*)(ws + 19398656);    // 4,194,304
  float* h = (float*)(ws + 23592960);         // 8,388,608
  bf16_t* hb = (bf16_t*)(ws + 31981568);      // 4,194,304
  float* f = (float*)(ws + 36175872);         // 8,388,608 (end 44,564,480)
  // CSR buffers alias the h region (h is written only after attention is done)
  uint* deg = (uint*)(ws + 23592960);         // 16,384
  int* colv = (int*)(ws + 23609344);          // 1,572,864
  uint* eidv = (uint*)(ws + 25182208);        // 1,572,864 (end 26,755,072 < h end)
  float* attn_out = (float*)(ws + 0);         // alias over dead qsplit

  cast_all_k<<<3328, 256, 0, stream>>>(x, Wqkv, Wo, W1, xb, Wqkvb, Wob, W1b, deg);
  fill_bucket_k<<<(E + 255) / 256, 256, 0, stream>>>(ei, deg, colv, eidv, E);

  // QKV projection with head-sliced K/V output
  gemm_bt<2><<<dim3(QKVD / 64, NNODES / 128), 256, 0, stream>>>(
      xb, Wqkvb, bqkv, (void*)qsplit, NNODES, QKVD, DIM);

  // head-group sparse attention (4 groups of 2 heads; per-group K+V slice = 2MB)
  attn_hg_k<<<dim3(NNODES, 4), 256, 0, stream>>>(qb, khp, vhp, ew, deg, colv, eidv, outb);

  // output projection (f32 out, aliases qsplit space)
  gemm_bt<0><<<dim3(DIM / 64, NNODES / 128), 256, 0, stream>>>(
      outb, Wob, bo, (void*)attn_out, NNODES, DIM, DIM);

  // LN1: h = LN(x + attn_out), also bf16 copy for FFN GEMM
  ln_k<<<NNODES, 64, 0, stream>>>(x, attn_out, g1, be1, h, hb);

  // FFN: f = hb @ W1^T + b1
  gemm_bt<0><<<dim3(DIM / 64, NNODES / 128), 256, 0, stream>>>(
      hb, W1b, b1, (void*)f, NNODES, DIM, DIM);

  // LN2 -> out
  ln_k<<<NNODES, 64, 0, stream>>>(h, f, g2, be2, out, nullptr);
}

// Round 8
// 129.631 us; speedup vs baseline: 1.2160x; 1.2160x over previous
//
#include <hip/hip_runtime.h>

#define NNODES 4096
#define DIM 512
#define QKVD 1536
#define MAXE 96  // bucket capacity per dst row (Poisson(32): P(deg>96) ~ 1e-18)

typedef __bf16 bf16_t;
typedef bf16_t bf16x8 __attribute__((ext_vector_type(8)));
typedef bf16_t bf16x2 __attribute__((ext_vector_type(2)));
typedef float f32x4 __attribute__((ext_vector_type(4)));
typedef unsigned int uint;

// ---------------- fused casts f32 -> bf16 (+ deg zero) ----------------
__global__ __launch_bounds__(256) void cast_all_k(const float* __restrict__ x,
                                                  const float* __restrict__ wqkv,
                                                  const float* __restrict__ wo,
                                                  const float* __restrict__ w1,
                                                  bf16_t* __restrict__ xb,
                                                  bf16_t* __restrict__ wqkvb,
                                                  bf16_t* __restrict__ wob,
                                                  bf16_t* __restrict__ w1b,
                                                  uint* __restrict__ deg) {
  int i = blockIdx.x * 256 + threadIdx.x;
  if (blockIdx.x < 16) deg[i] = 0u;  // 16*256 = 4096 rows
  const float* src;
  bf16_t* dst;
  int off;
  if (i < 524288) { src = x; dst = xb; off = i; }
  else if (i < 720896) { src = wqkv; dst = wqkvb; off = i - 524288; }
  else if (i < 786432) { src = wo; dst = wob; off = i - 720896; }
  else { src = w1; dst = w1b; off = i - 786432; }
  float4 v = ((const float4*)src)[off];
  dst[4 * off + 0] = (bf16_t)v.x;
  dst[4 * off + 1] = (bf16_t)v.y;
  dst[4 * off + 2] = (bf16_t)v.z;
  dst[4 * off + 3] = (bf16_t)v.w;
}

// ---------------- bucket CSR fill ----------------
__global__ __launch_bounds__(256) void fill_bucket_k(const int* __restrict__ ei,
                                                     uint* __restrict__ deg,
                                                     int* __restrict__ colv,
                                                     uint* __restrict__ eidv, int E) {
  int e = blockIdx.x * 256 + threadIdx.x;
  if (e < E) {
    int src = ei[e] & (NNODES - 1);
    int dst = ei[E + e] & (NNODES - 1);
    uint pos = atomicAdd(&deg[dst], 1u);
    if (pos < MAXE) {
      colv[dst * MAXE + pos] = src;
      eidv[dst * MAXE + pos] = (uint)e + 1u;  // 0 reserved for diagonal self-entry
    }
  }
}

// ---------------- bf16 MFMA GEMM: C = A @ B^T + bias, tile 128x64 ----------------
template <bool OUT_BF16>
__global__ __launch_bounds__(256) void gemm_bt(const bf16_t* __restrict__ A,
                                               const bf16_t* __restrict__ B,
                                               const float* __restrict__ bias,
                                               void* __restrict__ Cout,
                                               int M, int Nt, int K) {
  __shared__ bf16_t As[128][40];
  __shared__ bf16_t Bs[64][40];
  const int t = threadIdx.x;
  const int lane = t & 63, w = t >> 6;
  const int wr = (w >> 1) * 64, wc = (w & 1) * 32;
  const int m0 = blockIdx.y * 128, n0 = blockIdx.x * 64;
  f32x4 acc[4][2] = {};
  const int r_ld = t >> 2;
  const int c_ld = (t & 3) * 8;

  for (int k0 = 0; k0 < K; k0 += 32) {
    *(int4*)&As[r_ld][c_ld] = *(const int4*)(A + (long)(m0 + r_ld) * K + k0 + c_ld);
    *(int4*)&As[r_ld + 64][c_ld] = *(const int4*)(A + (long)(m0 + r_ld + 64) * K + k0 + c_ld);
    *(int4*)&Bs[r_ld][c_ld] = *(const int4*)(B + (long)(n0 + r_ld) * K + k0 + c_ld);
    __syncthreads();
    bf16x8 af[4], bfr[2];
    const int kg = (lane >> 4) * 8;
#pragma unroll
    for (int i = 0; i < 4; ++i)
      af[i] = *(const bf16x8*)&As[wr + i * 16 + (lane & 15)][kg];
#pragma unroll
    for (int j = 0; j < 2; ++j)
      bfr[j] = *(const bf16x8*)&Bs[wc + j * 16 + (lane & 15)][kg];
#pragma unroll
    for (int i = 0; i < 4; ++i)
#pragma unroll
      for (int j = 0; j < 2; ++j)
        acc[i][j] = __builtin_amdgcn_mfma_f32_16x16x32_bf16(af[i], bfr[j], acc[i][j], 0, 0, 0);
    __syncthreads();
  }

  const int cr = (lane >> 4) * 4;
  const int cc = lane & 15;
#pragma unroll
  for (int i = 0; i < 4; ++i) {
#pragma unroll
    for (int j = 0; j < 2; ++j) {
      int n = n0 + wc + j * 16 + cc;
      float bv = bias[n];
#pragma unroll
      for (int r = 0; r < 4; ++r) {
        int m = m0 + wr + i * 16 + cr + r;
        float vv = acc[i][j][r] + bv;
        if (OUT_BF16)
          ((bf16_t*)Cout)[(long)m * Nt + n] = (bf16_t)vv;
        else
          ((float*)Cout)[(long)m * Nt + n] = vv;
      }
    }
  }
}

// ---------------- fused sparse attention: scores + softmax + PV ----------------
// one block (512 thr, 8 waves) per dst row; ALL gather loads (K,V,bias) issued up
// front into registers (8 entries/wave covers n<=64; rare tail uses inline loads)
__global__ __launch_bounds__(512) void attn_fused_k(const bf16_t* __restrict__ qkv,
                                                    const float* __restrict__ ew,
                                                    const uint* __restrict__ deg,
                                                    const int* __restrict__ colv,
                                                    const uint* __restrict__ eidv,
                                                    bf16_t* __restrict__ outb) {
  __shared__ float scs[8][MAXE + 1];
  __shared__ int srcs[MAXE + 1];
  __shared__ uint eids[MAXE + 1];
  __shared__ int vld[MAXE + 1];
  __shared__ float invs_s[8];
  __shared__ float vacc[8][DIM];

  const int i = blockIdx.x;
  const int t = threadIdx.x;
  const int lane = t & 63, w = t >> 6;  // w in 0..7

  uint dg = deg[i];
  int L = (dg < (uint)MAXE) ? (int)dg : MAXE;
  int n = L + 1;

  if (t < L) {
    srcs[t] = colv[i * MAXE + t];
    eids[t] = eidv[i * MAXE + t];
  }
  if (t == L) { srcs[L] = i; eids[L] = 0u; }
  __syncthreads();

  // ---- prefetch: wave w owns entries e = w + 8u, u = 0..7 (covers n <= 64) ----
  const bf16x8 qv = *(const bf16x8*)(qkv + (long)i * QKVD + lane * 8);
  int val[8], ec[8];
#pragma unroll
  for (int u = 0; u < 8; ++u) {
    int ee = w + 8 * u;
    val[u] = ee < n;
    ec[u] = val[u] ? ee : 0;
  }
  bf16x8 kpre[8], vpre[8];
#pragma unroll
  for (int u = 0; u < 8; ++u) {
    long rb = (long)srcs[ec[u]] * QKVD;
    kpre[u] = *(const bf16x8*)(qkv + rb + DIM + lane * 8);
    vpre[u] = *(const bf16x8*)(qkv + rb + 2 * DIM + lane * 8);
  }
  float bpre[8];
#pragma unroll
  for (int u = 0; u < 8; ++u) {
    uint id = eids[ec[u]];
    bpre[u] = (id == 0u) ? 0.f : ew[id - 1u];
  }

  // ---- dedupe (last edge-id wins per src) overlaps the loads; t<n only ----
  if (t < n) {
    int sj = srcs[t];
    uint my = eids[t];
    int ok = 1;
    for (int j = 0; j < n; ++j)
      ok &= !((srcs[j] == sj) & (eids[j] > my));
    vld[t] = ok;
  }
  __syncthreads();

  // ---- scores from prefetched K ----
#pragma unroll
  for (int u = 0; u < 8; ++u) {
    float d = 0.f;
#pragma unroll
    for (int j = 0; j < 8; ++j) d += (float)qv[j] * (float)kpre[u][j];
#pragma unroll
    for (int o = 1; o < 8; o <<= 1) d += __shfl_xor(d, o);
    if (((lane & 7) == 0) & val[u]) {
      int e = w + 8 * u;
      scs[lane >> 3][e] = vld[e] ? (d * 0.125f + bpre[u]) : -1e30f;
    }
  }
  // tail (n > 64): inline loads
  for (int e = w + 64; e < n; e += 8) {
    const bf16x8 ka = *(const bf16x8*)(qkv + (long)srcs[e] * QKVD + DIM + lane * 8);
    float d = 0.f;
#pragma unroll
    for (int j = 0; j < 8; ++j) d += (float)qv[j] * (float)ka[j];
#pragma unroll
    for (int o = 1; o < 8; o <<= 1) d += __shfl_xor(d, o);
    if ((lane & 7) == 0) {
      uint id = eids[e];
      float b = (id == 0u) ? 0.f : ew[id - 1u];
      scs[lane >> 3][e] = vld[e] ? (d * 0.125f + b) : -1e30f;
    }
  }
  __syncthreads();

  // ---- softmax: wave w handles head w (n <= 97 -> at most 2 entries/lane) ----
  {
    float m = -1e30f;
    for (int e = lane; e < n; e += 64) m = fmaxf(m, scs[w][e]);
#pragma unroll
    for (int o = 32; o > 0; o >>= 1) m = fmaxf(m, __shfl_xor(m, o));
    float ps = 0.f;
    for (int e = lane; e < n; e += 64) {
      float ev = __expf(scs[w][e] - m);
      scs[w][e] = ev;  // invalid entries become exactly 0
      ps += ev;
    }
#pragma unroll
    for (int o = 32; o > 0; o >>= 1) ps += __shfl_xor(ps, o);
    if (lane == 0) invs_s[w] = 1.f / ps;
  }
  __syncthreads();

  // ---- PV from prefetched V; p = 0 for clamped/invalid slots ----
  const int hl = lane >> 3;
  float a8[8] = {0.f, 0.f, 0.f, 0.f, 0.f, 0.f, 0.f, 0.f};
#pragma unroll
  for (int u = 0; u < 8; ++u) {
    float p = val[u] ? scs[hl][w + 8 * u] : 0.f;
#pragma unroll
    for (int j = 0; j < 8; ++j) a8[j] += p * (float)vpre[u][j];
  }
  // tail (n > 64)
  for (int e = w + 64; e < n; e += 8) {
    const bf16x8 vv = *(const bf16x8*)(qkv + (long)srcs[e] * QKVD + 2 * DIM + lane * 8);
    float p = scs[hl][e];
#pragma unroll
    for (int j = 0; j < 8; ++j) a8[j] += p * (float)vv[j];
  }
#pragma unroll
  for (int j = 0; j < 8; ++j) vacc[w][lane * 8 + j] = a8[j];
  __syncthreads();

  // final reduce over 8 wave-partials: thread t -> dim t
  {
    float s = 0.f;
#pragma unroll
    for (int ww = 0; ww < 8; ++ww) s += vacc[ww][t];
    outb[(long)i * DIM + t] = (bf16_t)(s * invs_s[t >> 6]);
  }
}

// ---------------- LayerNorm(a+b) ----------------
__global__ __launch_bounds__(64) void ln_k(const float* __restrict__ a,
                                           const float* __restrict__ b,
                                           const float* __restrict__ g,
                                           const float* __restrict__ beta,
                                           float* __restrict__ of,
                                           bf16_t* __restrict__ ob) {
  const int row = blockIdx.x;
  const int l = threadIdx.x;
  const float* pa = a + (long)row * DIM;
  const float* pb = b + (long)row * DIM;
  float v[8];
  float s = 0.f;
#pragma unroll
  for (int j = 0; j < 8; ++j) {
    int d = l + j * 64;
    v[j] = pa[d] + pb[d];
    s += v[j];
  }
#pragma unroll
  for (int o = 32; o > 0; o >>= 1) s += __shfl_xor(s, o);
  float mu = s * (1.f / 512.f);
  float q = 0.f;
#pragma unroll
  for (int j = 0; j < 8; ++j) {
    float dd = v[j] - mu;
    q += dd * dd;
  }
#pragma unroll
  for (int o = 32; o > 0; o >>= 1) q += __shfl_xor(q, o);
  float inv = rsqrtf(q * (1.f / 512.f) + 1e-5f);
#pragma unroll
  for (int j = 0; j < 8; ++j) {
    int d = l + j * 64;
    float y = (v[j] - mu) * inv * g[d] + beta[d];
    of[(long)row * DIM + d] = y;
    if (ob) ob[(long)row * DIM + d] = (bf16_t)y;
  }
}

// ---------------- launch ----------------
extern "C" void kernel_launch(void* const* d_in, const int* in_sizes, int n_in,
                              void* d_out, int out_size, void* d_ws, size_t ws_size,
                              hipStream_t stream) {
  const float* x = (const float*)d_in[0];
  const int* ei = (const int*)d_in[1];
  const float* ew = (const float*)d_in[2];
  const float* Wqkv = (const float*)d_in[3];
  const float* bqkv = (const float*)d_in[4];
  const float* Wo = (const float*)d_in[5];
  const float* bo = (const float*)d_in[6];
  const float* W1 = (const float*)d_in[7];
  const float* b1 = (const float*)d_in[8];
  const float* g1 = (const float*)d_in[9];
  const float* be1 = (const float*)d_in[10];
  const float* g2 = (const float*)d_in[11];
  const float* be2 = (const float*)d_in[12];
  float* out = (float*)d_out;
  const int E = in_sizes[1] / 2;

  char* ws = (char*)d_ws;
  bf16_t* qkvb = (bf16_t*)(ws + 0);           // 12,582,912 B
  bf16_t* xb = (bf16_t*)(ws + 12582912);      // 4,194,304
  bf16_t* Wqkvb = (bf16_t*)(ws + 16777216);   // 1,572,864
  bf16_t* Wob = (bf16_t*)(ws + 18350080);     // 524,288
  bf16_t* W1b = (bf16_t*)(ws + 18874368);     // 524,288
  bf16_t* outb = (bf16_t*)(ws + 19398656);    // 4,194,304
  float* h = (float*)(ws + 23592960);         // 8,388,608
  bf16_t* hb = (bf16_t*)(ws + 31981568);      // 4,194,304
  float* f = (float*)(ws + 36175872);         // 8,388,608 (end 44,564,480)
  // CSR buffers alias the h region (h is written only after attention is done)
  uint* deg = (uint*)(ws + 23592960);         // 16,384
  int* colv = (int*)(ws + 23609344);          // 1,572,864
  uint* eidv = (uint*)(ws + 25182208);        // 1,572,864 (end 26,755,072 < h end)
  float* attn_out = (float*)(ws + 0);         // alias over dead qkvb

  cast_all_k<<<3328, 256, 0, stream>>>(x, Wqkv, Wo, W1, xb, Wqkvb, Wob, W1b, deg);
  fill_bucket_k<<<(E + 255) / 256, 256, 0, stream>>>(ei, deg, colv, eidv, E);

  // QKV projection (bf16 out): 24 x 32 = 768 blocks
  gemm_bt<true><<<dim3(QKVD / 64, NNODES / 128), 256, 0, stream>>>(
      xb, Wqkvb, bqkv, (void*)qkvb, NNODES, QKVD, DIM);

  // fused sparse attention (8 waves per row, full prefetch)
  attn_fused_k<<<NNODES, 512, 0, stream>>>(qkvb, ew, deg, colv, eidv, outb);

  // output projection (f32 out, aliases qkvb space): 8 x 32 = 256 blocks
  gemm_bt<false><<<dim3(DIM / 64, NNODES / 128), 256, 0, stream>>>(
      outb, Wob, bo, (void*)attn_out, NNODES, DIM, DIM);

  // LN1: h = LN(x + attn_out), also bf16 copy for FFN GEMM
  ln_k<<<NNODES, 64, 0, stream>>>(x, attn_out, g1, be1, h, hb);

  // FFN: f = hb @ W1^T + b1
  gemm_bt<false><<<dim3(DIM / 64, NNODES / 128), 256, 0, stream>>>(
      hb, W1b, b1, (void*)f, NNODES, DIM, DIM);

  // LN2 -> out
  ln_k<<<NNODES, 64, 0, stream>>>(h, f, g2, be2, out, nullptr);
}